// Round 1
// baseline (25271.555 us; speedup 1.0000x reference)
//
#include <hip/hip_runtime.h>
#include <math.h>

#define BB_   64     // batch
#define TT_   256    // time steps
#define DIN_  256
#define HH_   512
#define NMEM_ 128
#define WWID_ 64     // word size
#define RR_   4      // read heads
#define DOUT_ 256
#define CTRL_ 512    // DIN + R*W
#define EPSV  1e-8f

__device__ __forceinline__ float sigm(float x){ return 1.f/(1.f+expf(-x)); }
__device__ __forceinline__ float softp(float x){ return (x>20.f)? x : log1pf(expf(x)); }
__device__ __forceinline__ float wredsum(float v){
  #pragma unroll
  for (int o=32;o>0;o>>=1) v += __shfl_xor(v,o,64);
  return v;
}
__device__ __forceinline__ float wredmax(float v){
  #pragma unroll
  for (int o=32;o>0;o>>=1) v = fmaxf(v, __shfl_xor(v,o,64));
  return v;
}

__global__ void k_zero(float* __restrict__ p, int n){
  int i = blockIdx.x*blockDim.x + threadIdx.x;
  if (i < n) p[i] = 0.f;
}

// x[b][t][k] (B,T,DIN) -> xT[(t*DIN + k)*64 + b]
__launch_bounds__(256)
__global__ void k_transpose_x(const float* __restrict__ x, float* __restrict__ xT)
{
  __shared__ float tile[64][65];
  const int t    = blockIdx.x >> 2;
  const int k0   = (blockIdx.x & 3) << 6;
  const int lane = threadIdx.x & 63;
  const int row  = threadIdx.x >> 6;
  #pragma unroll
  for (int i = 0; i < 16; ++i) {
    int bb = row + (i<<2);
    tile[bb][lane] = x[(size_t)bb*(TT_*DIN_) + (size_t)t*DIN_ + k0 + lane];
  }
  __syncthreads();
  #pragma unroll
  for (int i = 0; i < 16; ++i) {
    int kk = row + (i<<2);
    xT[(size_t)(t*DIN_ + k0 + kk)*64 + lane] = tile[lane][kk];
  }
}

// gates + LSTM cell. grid = H (one block per hidden unit j), block = 256 (lane=b, wave=gate)
template<bool USE_XT>
__launch_bounds__(256)
__global__ void k_step1(const float* __restrict__ x, const float* __restrict__ xT,
                        const float* __restrict__ Wih, const float* __restrict__ Whh,
                        const float* __restrict__ bih, const float* __restrict__ bhh,
                        const float* __restrict__ hR, float* __restrict__ hW,
                        float* __restrict__ cT, const float* __restrict__ rvT, int t)
{
  const int tid = threadIdx.x;
  const int b   = tid & 63;
  const int g   = tid >> 6;      // 0..3 : i,f,g,o
  const int j   = blockIdx.x;    // 0..511
  const int row = g*HH_ + j;
  float acc = bih[row] + bhh[row];
  const float* wih = Wih + (size_t)row*CTRL_;
  const float* whh = Whh + (size_t)row*HH_;

  if (USE_XT) {
    const float* xr = xT + (size_t)t*DIN_*64;
    #pragma unroll 4
    for (int k = 0; k < DIN_; k += 4) {
      float4 w = *(const float4*)(wih + k);
      acc += w.x*xr[(k+0)*64+b] + w.y*xr[(k+1)*64+b]
           + w.z*xr[(k+2)*64+b] + w.w*xr[(k+3)*64+b];
    }
  } else {
    const float* xr = x + (size_t)(b*TT_ + t)*DIN_;
    #pragma unroll 4
    for (int k = 0; k < DIN_; k += 4) {
      float4 w  = *(const float4*)(wih + k);
      float4 xv = *(const float4*)(xr + k);
      acc += w.x*xv.x + w.y*xv.y + w.z*xv.z + w.w*xv.w;
    }
  }
  #pragma unroll 4
  for (int k = 0; k < RR_*WWID_; k += 4) {
    float4 w = *(const float4*)(wih + DIN_ + k);
    acc += w.x*rvT[(k+0)*64+b] + w.y*rvT[(k+1)*64+b]
         + w.z*rvT[(k+2)*64+b] + w.w*rvT[(k+3)*64+b];
  }
  #pragma unroll 4
  for (int k = 0; k < HH_; k += 4) {
    float4 w = *(const float4*)(whh + k);
    acc += w.x*hR[(k+0)*64+b] + w.y*hR[(k+1)*64+b]
         + w.z*hR[(k+2)*64+b] + w.w*hR[(k+3)*64+b];
  }

  __shared__ float gbuf[4][64];
  gbuf[g][b] = acc;
  __syncthreads();
  if (g == 0) {
    float ig = gbuf[0][b], fg = gbuf[1][b], gg = gbuf[2][b], og = gbuf[3][b];
    float c  = cT[j*64 + b];
    float cn = sigm(fg)*c + sigm(ig)*tanhf(gg);
    float hn = sigm(og)*tanhf(cn);
    cT[j*64 + b] = cn;
    hW[j*64 + b] = hn;
  }
}

// iface = h @ W_int^T + b_int (raw, activations applied in step3). 453 useful outputs.
__launch_bounds__(256)
__global__ void k_step2(const float* __restrict__ Wint, const float* __restrict__ bint,
                        const float* __restrict__ h, float* __restrict__ ifc)
{
  const int tid = threadIdx.x;
  const int b   = tid & 63;
  const int o   = blockIdx.x*4 + (tid>>6);
  if (o >= 453) return;
  const float* w = Wint + (size_t)o*HH_;
  float acc = bint[o];
  #pragma unroll 4
  for (int k = 0; k < HH_; k += 4) {
    float4 wv = *(const float4*)(w + k);
    acc += wv.x*h[(k+0)*64+b] + wv.y*h[(k+1)*64+b]
         + wv.z*h[(k+2)*64+b] + wv.w*h[(k+3)*64+b];
  }
  ifc[o*64 + b] = acc;
}

// content addressing + memory update + reads. one block per batch element.
__launch_bounds__(256)
__global__ void k_step3(const float* __restrict__ ifc, float* __restrict__ mem,
                        float* __restrict__ rvT)
{
  const int b    = blockIdx.x;
  const int tid  = threadIdx.x;
  const int lane = tid & 63;
  const int wv   = tid >> 6;

  __shared__ float memS[NMEM_][WWID_];
  __shared__ float aS[NMEM_];
  __shared__ float rS[RR_][NMEM_];
  __shared__ float wwS[NMEM_];

  float* gm = mem + (size_t)b*NMEM_*WWID_;
  for (int i = tid; i < NMEM_*WWID_; i += 256)
    memS[i>>6][i&63] = gm[i];

  const float wkey = ifc[(260+lane)*64 + b];
  const float er   = sigm(ifc[(325+lane)*64 + b]);
  const float wvec = ifc[(389+lane)*64 + b];
  float rkey[RR_], rstr[RR_], nkr[RR_];
  #pragma unroll
  for (int r = 0; r < RR_; ++r) rkey[r] = ifc[(r*64+lane)*64 + b];
  const float wstr = softp(ifc[324*64 + b]) + 1.f;
  #pragma unroll
  for (int r = 0; r < RR_; ++r) rstr[r] = softp(ifc[(256+r)*64 + b]) + 1.f;

  const float nkw = fmaxf(sqrtf(wredsum(wkey*wkey)), EPSV);
  #pragma unroll
  for (int r = 0; r < RR_; ++r) nkr[r] = fmaxf(sqrtf(wredsum(rkey[r]*rkey[r])), EPSV);

  __syncthreads();

  // write-head scores
  for (int n = wv; n < NMEM_; n += 4) {
    float m = memS[n][lane];
    float d = wredsum(wkey*m);
    float q = wredsum(m*m);
    if (lane == 0)
      aS[n] = wstr * d / (nkw * fmaxf(sqrtf(q), EPSV));
  }
  __syncthreads();

  // softmax over 128 slots (wave 0)
  if (wv == 0) {
    float v0 = aS[lane], v1 = aS[lane+64];
    float mx = wredmax(fmaxf(v0, v1));
    float e0 = expf(v0-mx), e1 = expf(v1-mx);
    float s  = wredsum(e0+e1);
    wwS[lane]    = e0/s;
    wwS[lane+64] = e1/s;
  }
  __syncthreads();

  // memory update + read-head scores (on updated memory)
  for (int n = wv; n < NMEM_; n += 4) {
    float w  = wwS[n];
    float m  = memS[n][lane];
    float mn = m*(1.f - w*er) + w*wvec;
    memS[n][lane] = mn;
    float nm = fmaxf(sqrtf(wredsum(mn*mn)), EPSV);
    #pragma unroll
    for (int r = 0; r < RR_; ++r) {
      float d = wredsum(rkey[r]*mn);
      if (lane == 0) rS[r][n] = rstr[r]*d/(nkr[r]*nm);
    }
  }
  __syncthreads();

  // read softmaxes: wave r handles head r
  {
    float v0 = rS[wv][lane], v1 = rS[wv][lane+64];
    float mx = wredmax(fmaxf(v0, v1));
    float e0 = expf(v0-mx), e1 = expf(v1-mx);
    float s  = wredsum(e0+e1);
    rS[wv][lane]    = e0/s;
    rS[wv][lane+64] = e1/s;
  }
  __syncthreads();

  // rv[r][w] = sum_n rw[r][n] * mem[n][w]
  {
    float acc = 0.f;
    for (int n = 0; n < NMEM_; ++n)
      acc += rS[wv][n]*memS[n][lane];
    rvT[(wv*64 + lane)*64 + b] = acc;
  }
  __syncthreads();
  for (int i = tid; i < NMEM_*WWID_; i += 256)
    gm[i] = memS[i>>6][i&63];
}

// final projection: out = [h | rv] @ W_out^T + b_out (only last step needed)
__launch_bounds__(256)
__global__ void k_out(const float* __restrict__ Wout, const float* __restrict__ bout,
                      const float* __restrict__ h, const float* __restrict__ rvT,
                      float* __restrict__ out)
{
  const int tid = threadIdx.x;
  const int b   = tid & 63;
  const int o   = blockIdx.x*4 + (tid>>6);
  const float* w = Wout + (size_t)o*(HH_ + RR_*WWID_);
  float acc = bout[o];
  #pragma unroll 4
  for (int k = 0; k < HH_; k += 4) {
    float4 wv = *(const float4*)(w + k);
    acc += wv.x*h[(k+0)*64+b] + wv.y*h[(k+1)*64+b]
         + wv.z*h[(k+2)*64+b] + wv.w*h[(k+3)*64+b];
  }
  #pragma unroll 4
  for (int k = 0; k < RR_*WWID_; k += 4) {
    float4 wv = *(const float4*)(w + HH_ + k);
    acc += wv.x*rvT[(k+0)*64+b] + wv.y*rvT[(k+1)*64+b]
         + wv.z*rvT[(k+2)*64+b] + wv.w*rvT[(k+3)*64+b];
  }
  out[(size_t)b*DOUT_ + o] = acc;
}

extern "C" void kernel_launch(void* const* d_in, const int* in_sizes, int n_in,
                              void* d_out, int out_size, void* d_ws, size_t ws_size,
                              hipStream_t stream)
{
  const float* x    = (const float*)d_in[0];
  const float* Wih  = (const float*)d_in[1];
  const float* Whh  = (const float*)d_in[2];
  const float* bih  = (const float*)d_in[3];
  const float* bhh  = (const float*)d_in[4];
  const float* Wint = (const float*)d_in[5];
  const float* bint = (const float*)d_in[6];
  const float* Wout = (const float*)d_in[7];
  const float* bout = (const float*)d_in[8];
  float* out = (float*)d_out;
  float* ws  = (float*)d_ws;

  const size_t nXT   = (size_t)TT_*DIN_*64;                 // 4,194,304 floats
  const size_t nStat = (size_t)3*HH_*64 + (size_t)BB_*NMEM_*WWID_ + (size_t)RR_*WWID_*64; // 638,976
  const size_t nIfc  = 465*64;
  const bool useXT = ws_size >= (nXT + nStat + nIfc)*sizeof(float);

  size_t off = 0;
  float* xT = ws; if (useXT) off = nXT;
  float* h0  = ws + off; off += (size_t)HH_*64;
  float* h1  = ws + off; off += (size_t)HH_*64;
  float* cT  = ws + off; off += (size_t)HH_*64;
  float* mem = ws + off; off += (size_t)BB_*NMEM_*WWID_;
  float* rvT = ws + off; off += (size_t)RR_*WWID_*64;
  float* ifc = ws + off; off += nIfc;

  // zero recurrent state (h0,h1,cT,mem,rvT are contiguous from h0)
  const int nz = (int)nStat;
  k_zero<<<(nz+255)/256, 256, 0, stream>>>(h0, nz);
  if (useXT)
    k_transpose_x<<<TT_*4, 256, 0, stream>>>(x, xT);

  float* hb[2] = {h0, h1};
  for (int t = 0; t < TT_; ++t) {
    const float* hR = hb[t&1];
    float*       hW = hb[(t+1)&1];
    if (useXT)
      k_step1<true ><<<HH_, 256, 0, stream>>>(x, xT, Wih, Whh, bih, bhh, hR, hW, cT, rvT, t);
    else
      k_step1<false><<<HH_, 256, 0, stream>>>(x, xT, Wih, Whh, bih, bhh, hR, hW, cT, rvT, t);
    k_step2<<<114, 256, 0, stream>>>(Wint, bint, hW, ifc);
    k_step3<<<BB_, 256, 0, stream>>>(ifc, mem, rvT);
  }
  k_out<<<DOUT_/4, 256, 0, stream>>>(Wout, bout, hb[0], rvT, out);
}